// Round 12
// baseline (36.729 us; speedup 1.0000x reference)
//
#include <hip/hip_runtime.h>

#define DIM 64
#define NPB 256           // nodes per bucket
#define NPB_SHIFT 8       // bin = dst >> 8
#define THREADS 512
#define K2_U 4
#define K2_EPB (THREADS * K2_U)   // 2048 edges per bin-block = strip size
#define STRIP K2_EPB
#define NODE_ROWS 160     // rows per node-score block (5 rows/thread)

// K1: per-node scores. 16 lanes/row, 5 rows/thread.
// s[i]   = dot(x[i], W_rel)
// out[i] = dot(x[i], W_root) + b_rel   (full overwrite -> replay-safe)
__global__ __launch_bounds__(THREADS)
void node_kernel(const float4* __restrict__ x4,
                 const float4* __restrict__ Wrel4,
                 const float* __restrict__ b_rel,
                 const float4* __restrict__ Wroot4,
                 float* __restrict__ s,
                 float* __restrict__ out,
                 int n) {
    int tid = threadIdx.x;
    int lane16 = tid & 15;
    int rg = tid >> 4;                  // 0..31
    int rowbase = blockIdx.x * NODE_ROWS + rg;
    float4 wr = Wrel4[lane16];
    float4 wt = Wroot4[lane16];
    float b0 = b_rel[0];

    float4 xv[5];
    int row[5];
    #pragma unroll
    for (int k = 0; k < 5; ++k) {
        row[k] = rowbase + k * 32;
        xv[k] = (row[k] < n) ? x4[(size_t)row[k] * (DIM / 4) + lane16]
                             : make_float4(0.f, 0.f, 0.f, 0.f);
    }
    #pragma unroll
    for (int k = 0; k < 5; ++k) {
        float sr = xv[k].x * wr.x + xv[k].y * wr.y
                 + xv[k].z * wr.z + xv[k].w * wr.w;
        float st = xv[k].x * wt.x + xv[k].y * wt.y
                 + xv[k].z * wt.z + xv[k].w * wt.w;
        #pragma unroll
        for (int off = 1; off < 16; off <<= 1) {
            sr += __shfl_xor(sr, off);
            st += __shfl_xor(st, off);
        }
        if (lane16 == 0 && row[k] < n) {
            s[row[k]]   = sr;
            out[row[k]] = st + b0;
        }
    }
}

// K2: bin+pack. Each block bin-sorts its 2048-edge chunk into a private
// dense strip of value-carrying pairs: (dstLocal<<24) | (f32bits>>8).
// Random s[src] gathers are issued early and hide behind hist/scan work
// at ~18 waves/CU occupancy.
__global__ __launch_bounds__(THREADS)
void bin_kernel(const int* __restrict__ ei,
                const float* __restrict__ s,
                unsigned* __restrict__ bucket,        // NBLK*STRIP uints
                unsigned short* __restrict__ offsT,   // (NB+1) x NBLK u16
                int E, int NB, int NBLK) {
    __shared__ __align__(16) unsigned lpair[K2_EPB];  // 8 KB
    __shared__ int  hist[THREADS];                    // 2 KB (then excl base)
    __shared__ int  wsum[8];

    int tid = threadIdx.x;
    int blk = blockIdx.x;
    hist[tid] = 0;
    __syncthreads();                                   // barrier 1

    int base = blk * K2_EPB + tid * K2_U;
    int dst[K2_U], rnk[K2_U], bin[K2_U];
    float val[K2_U];
    int have = 0;

    if (base + K2_U <= E) {
        const int4* sv = (const int4*)ei;              // src row
        const int4* dv = (const int4*)(ei + E);        // dst row
        int g = base >> 2;                             // = blk*512 + tid
        int4 s0 = sv[g];
        int4 d0 = dv[g];
        // issue the 4 independent random gathers immediately
        val[0] = s[s0.x]; val[1] = s[s0.y]; val[2] = s[s0.z]; val[3] = s[s0.w];
        dst[0] = d0.x; dst[1] = d0.y; dst[2] = d0.z; dst[3] = d0.w;
        have = K2_U;
    } else {
        #pragma unroll
        for (int k = 0; k < K2_U; ++k) {
            int e = base + k;
            if (e < E) {
                val[k] = s[ei[e]];
                dst[k] = ei[E + e];
                have = k + 1;
            }
        }
    }

    #pragma unroll
    for (int k = 0; k < K2_U; ++k) {
        if (k < have) {
            bin[k] = dst[k] >> NPB_SHIFT;
            rnk[k] = atomicAdd(&hist[bin[k]], 1);
        }
    }
    __syncthreads();                                   // barrier 2

    int h = hist[tid];

    // per-wave inclusive scan (no barriers)
    int lane = tid & 63;
    int w = tid >> 6;
    int incl = h;
    #pragma unroll
    for (int off = 1; off < 64; off <<= 1) {
        int v = __shfl_up(incl, off);
        if (lane >= off) incl += v;
    }
    if (lane == 63) wsum[w] = incl;
    __syncthreads();                                   // barrier 3

    int wb = 0;
    #pragma unroll
    for (int i = 0; i < 8; ++i) wb += (i < w) ? wsum[i] : 0;
    int excl = wb + incl - h;                          // exclusive scan

    // transposed offsets: offsT[bin][blk]; row NB holds strip totals.
    if (tid <= NB)
        offsT[(size_t)tid * NBLK + blk] = (unsigned short)excl;

    hist[tid] = excl;                                  // compaction base
    __syncthreads();                                   // barrier 4

    #pragma unroll
    for (int k = 0; k < K2_U; ++k) {
        if (k < have) {
            int slot = hist[bin[k]] + rnk[k];          // bin-ordered LDS slot
            unsigned bits = __float_as_uint(val[k]);
            lpair[slot] = ((unsigned)(dst[k] & (NPB - 1)) << 24) | (bits >> 8);
        }
    }
    __syncthreads();                                   // barrier 5

    // dense, perfectly-coalesced strip dump (1 uint4 per thread)
    int nE = min(K2_EPB, E - blk * K2_EPB);
    int n4 = (nE + 3) >> 2;
    const uint4* lp4 = (const uint4*)lpair;
    uint4* dp4 = (uint4*)(bucket + (size_t)blk * STRIP);
    for (int i = tid; i < n4; i += THREADS) dp4[i] = lp4[i];
}

// K3: pure-streaming gather. Stage offs rows b,b+1 into LDS; thread t walks
// strips t, t+512 with uint4 loads; decode (dst = p>>24, v = bits(p<<8));
// LDS accumulate; plain RMW of disjoint out slice. Zero random loads.
__global__ __launch_bounds__(THREADS)
void gather_kernel(const unsigned short* __restrict__ offsT,
                   const unsigned* __restrict__ bucket,
                   float* __restrict__ out,
                   int NB, int NBLK, int n) {
    __shared__ float acc[NPB];
    __shared__ unsigned short o0s[640], o1s[640];
    int b = blockIdx.x;
    int tid = threadIdx.x;

    if (tid < NPB) acc[tid] = 0.f;
    for (int t = tid; t < NBLK; t += THREADS) {
        o0s[t] = offsT[(size_t)b * NBLK + t];          // coalesced row reads
        o1s[t] = offsT[(size_t)(b + 1) * NBLK + t];
    }
    __syncthreads();

    for (int st = tid; st < NBLK; st += THREADS) {
        int o0 = o0s[st];
        int o1 = o1s[st];
        const unsigned* sp = bucket + (size_t)st * STRIP;
        int i = o0;
        for (; i < o1 && (i & 3); ++i) {
            unsigned p = sp[i];
            atomicAdd(&acc[p >> 24], __uint_as_float(p << 8));
        }
        for (; i + 4 <= o1; i += 4) {
            uint4 q = *(const uint4*)(sp + i);
            atomicAdd(&acc[q.x >> 24], __uint_as_float(q.x << 8));
            atomicAdd(&acc[q.y >> 24], __uint_as_float(q.y << 8));
            atomicAdd(&acc[q.z >> 24], __uint_as_float(q.z << 8));
            atomicAdd(&acc[q.w >> 24], __uint_as_float(q.w << 8));
        }
        for (; i < o1; ++i) {
            unsigned p = sp[i];
            atomicAdd(&acc[p >> 24], __uint_as_float(p << 8));
        }
    }
    __syncthreads();

    if (tid < NPB) {
        int g = b * NPB + tid;
        if (g < n) out[g] += acc[tid];
    }
}

extern "C" void kernel_launch(void* const* d_in, const int* in_sizes, int n_in,
                              void* d_out, int out_size, void* d_ws, size_t ws_size,
                              hipStream_t stream) {
    const float* x      = (const float*)d_in[0];
    const int*   ei     = (const int*)d_in[1];
    const float* W_rel  = (const float*)d_in[2];
    const float* b_rel  = (const float*)d_in[3];
    const float* W_root = (const float*)d_in[4];
    float* out = (float*)d_out;

    int n = out_size;                 // N_NODES = 100000
    int E = in_sizes[1] / 2;          // 1200000

    int NB   = (n + NPB - 1) / NPB;          // 391 buckets (<= THREADS)
    int NBLK = (E + K2_EPB - 1) / K2_EPB;    // 586 strips

    // ws layout: s [n f32] | offsT [(NB+1)*NBLK u16] | bucket [NBLK*STRIP u32]
    float* s = (float*)d_ws;
    size_t off = ((size_t)n * 4 + 255) & ~(size_t)255;
    unsigned short* offsT = (unsigned short*)((char*)d_ws + off);
    off += ((size_t)(NB + 1) * NBLK * 2 + 255) & ~(size_t)255;
    unsigned* bucket = (unsigned*)((char*)d_ws + off);

    // 1) node scores + out init
    int NODEBLKS = (n + NODE_ROWS - 1) / NODE_ROWS;  // 625
    node_kernel<<<NODEBLKS, THREADS, 0, stream>>>(
        (const float4*)x, (const float4*)W_rel, b_rel, (const float4*)W_root,
        s, out, n);

    // 2) bin + value-pack into dense strips
    bin_kernel<<<NBLK, THREADS, 0, stream>>>(ei, s, bucket, offsT, E, NB, NBLK);

    // 3) pure-streaming per-bucket accumulate + disjoint out RMW
    gather_kernel<<<NB, THREADS, 0, stream>>>(offsT, bucket, out, NB, NBLK, n);
}

// Round 13
// 33.200 us; speedup vs baseline: 1.1063x; 1.1063x over previous
//
#include <hip/hip_runtime.h>

#define DIM 64
#define NPB 256           // nodes per bucket
#define NPB_SHIFT 8       // bin = dst >> 8
#define THREADS 512
#define K2_U 4
#define K2_EPB (THREADS * K2_U)   // 2048 edges per bin-block = strip size
#define STRIP K2_EPB
#define SRC_BITS 17
#define SRC_MASK ((1u << SRC_BITS) - 1u)
#define NODE_ROWS 256     // rows per node-score block (8 rows/thread)

// Fused kernel: blocks [0,NBLK) bin-sort their 2048-edge chunk into a private
// dense strip (no global atomics, no cursors); blocks [NBLK,...) compute
// per-node scores + out init. Phases are data-independent.
// Total blocks 586+391=977 <= 1024 resident -> single dispatch round.
__global__ __launch_bounds__(THREADS)
void fused_kernel(const float4* __restrict__ x4,
                  const float4* __restrict__ Wrel4,
                  const float* __restrict__ b_rel,
                  const float4* __restrict__ Wroot4,
                  const int* __restrict__ ei,
                  float* __restrict__ s,
                  float* __restrict__ out,
                  unsigned* __restrict__ bucket,        // NBLK*STRIP uints
                  unsigned short* __restrict__ offsT,   // (NB+1) x NBLK u16
                  int E, int NB, int NBLK, int n) {
    __shared__ __align__(16) unsigned lpair[K2_EPB];  // 8 KB
    __shared__ int  hist[THREADS];                    // 2 KB (then excl base)
    __shared__ int  wsum[8];

    int tid = threadIdx.x;

    if (blockIdx.x < NBLK) {
        // ---------------- binning phase ----------------
        int blk = blockIdx.x;
        hist[tid] = 0;
        __syncthreads();                               // barrier 1

        int base = blk * K2_EPB + tid * K2_U;
        int dst[K2_U], src[K2_U], rnk[K2_U], bin[K2_U];
        int have = 0;

        if (base + K2_U <= E) {
            const int4* sv = (const int4*)ei;          // src row
            const int4* dv = (const int4*)(ei + E);    // dst row
            int g = base >> 2;                         // = blk*512 + tid
            int4 s0 = sv[g];
            int4 d0 = dv[g];
            src[0] = s0.x; src[1] = s0.y; src[2] = s0.z; src[3] = s0.w;
            dst[0] = d0.x; dst[1] = d0.y; dst[2] = d0.z; dst[3] = d0.w;
            have = K2_U;
        } else {
            #pragma unroll
            for (int k = 0; k < K2_U; ++k) {
                int e = base + k;
                if (e < E) {
                    src[k] = ei[e];
                    dst[k] = ei[E + e];
                    have = k + 1;
                }
            }
        }

        #pragma unroll
        for (int k = 0; k < K2_U; ++k) {
            if (k < have) {
                bin[k] = dst[k] >> NPB_SHIFT;
                rnk[k] = atomicAdd(&hist[bin[k]], 1);
            }
        }
        __syncthreads();                               // barrier 2

        int h = hist[tid];

        // per-wave inclusive scan (no barriers)
        int lane = tid & 63;
        int w = tid >> 6;
        int incl = h;
        #pragma unroll
        for (int off = 1; off < 64; off <<= 1) {
            int v = __shfl_up(incl, off);
            if (lane >= off) incl += v;
        }
        if (lane == 63) wsum[w] = incl;
        __syncthreads();                               // barrier 3

        int wb = 0;
        #pragma unroll
        for (int i = 0; i < 8; ++i) wb += (i < w) ? wsum[i] : 0;
        int excl = wb + incl - h;                      // exclusive scan

        // transposed offsets: offsT[bin][blk] (scattered stores, fire&forget;
        // gather reads each row contiguously). Row NB holds strip totals.
        if (tid <= NB)
            offsT[(size_t)tid * NBLK + blk] = (unsigned short)excl;

        hist[tid] = excl;                              // compaction base
        __syncthreads();                               // barrier 4

        #pragma unroll
        for (int k = 0; k < K2_U; ++k) {
            if (k < have) {
                int slot = hist[bin[k]] + rnk[k];      // bin-ordered LDS slot
                lpair[slot] = ((unsigned)(dst[k] & (NPB - 1)) << SRC_BITS)
                              | (unsigned)src[k];
            }
        }
        __syncthreads();                               // barrier 5

        // dense, perfectly-coalesced strip dump (1 uint4 per thread)
        int nE = min(K2_EPB, E - blk * K2_EPB);
        int n4 = (nE + 3) >> 2;
        const uint4* lp4 = (const uint4*)lpair;
        uint4* dp4 = (uint4*)(bucket + (size_t)blk * STRIP);
        for (int i = tid; i < n4; i += THREADS) dp4[i] = lp4[i];
    } else {
        // ---------------- node-score phase ----------------
        int nb = blockIdx.x - NBLK;
        int lane16 = tid & 15;
        int rg = tid >> 4;                  // 0..31
        int rowbase = nb * NODE_ROWS + rg;
        float4 wr = Wrel4[lane16];
        float4 wt = Wroot4[lane16];
        float b0 = b_rel[0];

        float4 xv[8];
        int row[8];
        #pragma unroll
        for (int k = 0; k < 8; ++k) {
            row[k] = rowbase + k * 32;
            xv[k] = (row[k] < n) ? x4[(size_t)row[k] * (DIM / 4) + lane16]
                                 : make_float4(0.f, 0.f, 0.f, 0.f);
        }
        #pragma unroll
        for (int k = 0; k < 8; ++k) {
            float sr = xv[k].x * wr.x + xv[k].y * wr.y
                     + xv[k].z * wr.z + xv[k].w * wr.w;
            float st = xv[k].x * wt.x + xv[k].y * wt.y
                     + xv[k].z * wt.z + xv[k].w * wt.w;
            #pragma unroll
            for (int off = 1; off < 16; off <<= 1) {
                sr += __shfl_xor(sr, off);
                st += __shfl_xor(st, off);
            }
            if (lane16 == 0 && row[k] < n) {
                s[row[k]]   = sr;
                out[row[k]] = st + b0;
            }
        }
    }
}

// Gather: one block per bucket. Stage offs rows b,b+1 (contiguous) into LDS;
// thread t walks strips t, t+512 with uint4-vectorized loads (all 512 lanes
// active: NBLK=586 >= THREADS); LDS accumulate; plain RMW of disjoint slice.
__global__ __launch_bounds__(THREADS)
void gather_kernel(const unsigned short* __restrict__ offsT,
                   const unsigned* __restrict__ bucket,
                   const float* __restrict__ s,
                   float* __restrict__ out,
                   int NB, int NBLK, int n) {
    __shared__ float acc[NPB];
    __shared__ unsigned short o0s[640], o1s[640];
    int b = blockIdx.x;
    int tid = threadIdx.x;

    if (tid < NPB) acc[tid] = 0.f;
    for (int t = tid; t < NBLK; t += THREADS) {
        o0s[t] = offsT[(size_t)b * NBLK + t];        // coalesced row read
        o1s[t] = offsT[(size_t)(b + 1) * NBLK + t];
    }
    __syncthreads();

    for (int st = tid; st < NBLK; st += THREADS) {
        int o0 = o0s[st];
        int o1 = o1s[st];
        const unsigned* sp = bucket + (size_t)st * STRIP;
        int i = o0;
        for (; i < o1 && (i & 3); ++i) {
            unsigned p = sp[i];
            atomicAdd(&acc[p >> SRC_BITS], s[p & SRC_MASK]);
        }
        for (; i + 4 <= o1; i += 4) {
            uint4 q = *(const uint4*)(sp + i);
            float v0 = s[q.x & SRC_MASK];
            float v1 = s[q.y & SRC_MASK];
            float v2 = s[q.z & SRC_MASK];
            float v3 = s[q.w & SRC_MASK];
            atomicAdd(&acc[q.x >> SRC_BITS], v0);
            atomicAdd(&acc[q.y >> SRC_BITS], v1);
            atomicAdd(&acc[q.z >> SRC_BITS], v2);
            atomicAdd(&acc[q.w >> SRC_BITS], v3);
        }
        for (; i < o1; ++i) {
            unsigned p = sp[i];
            atomicAdd(&acc[p >> SRC_BITS], s[p & SRC_MASK]);
        }
    }
    __syncthreads();

    if (tid < NPB) {
        int g = b * NPB + tid;
        if (g < n) out[g] += acc[tid];
    }
}

extern "C" void kernel_launch(void* const* d_in, const int* in_sizes, int n_in,
                              void* d_out, int out_size, void* d_ws, size_t ws_size,
                              hipStream_t stream) {
    const float* x      = (const float*)d_in[0];
    const int*   ei     = (const int*)d_in[1];
    const float* W_rel  = (const float*)d_in[2];
    const float* b_rel  = (const float*)d_in[3];
    const float* W_root = (const float*)d_in[4];
    float* out = (float*)d_out;

    int n = out_size;                 // N_NODES = 100000
    int E = in_sizes[1] / 2;          // 1200000

    int NB   = (n + NPB - 1) / NPB;          // 391 buckets (<= THREADS)
    int NBLK = (E + K2_EPB - 1) / K2_EPB;    // 586 strips

    // ws layout: s [n f32] | offsT [(NB+1)*NBLK u16] | bucket [NBLK*STRIP u32]
    float* s = (float*)d_ws;
    size_t off = ((size_t)n * 4 + 255) & ~(size_t)255;
    unsigned short* offsT = (unsigned short*)((char*)d_ws + off);
    off += ((size_t)(NB + 1) * NBLK * 2 + 255) & ~(size_t)255;
    unsigned* bucket = (unsigned*)((char*)d_ws + off);

    // 1) fused: strip-binning blocks + node-score blocks (977 blocks total)
    int NODEBLKS = (n + NODE_ROWS - 1) / NODE_ROWS;  // 391
    fused_kernel<<<NBLK + NODEBLKS, THREADS, 0, stream>>>(
        (const float4*)x, (const float4*)W_rel, b_rel, (const float4*)W_root,
        ei, s, out, bucket, offsT, E, NB, NBLK, n);

    // 2) per-bucket run-walk accumulate + disjoint out RMW
    gather_kernel<<<NB, THREADS, 0, stream>>>(offsT, bucket, s, out, NB, NBLK, n);
}

// Round 14
// 28.356 us; speedup vs baseline: 1.2953x; 1.1709x over previous
//
#include <hip/hip_runtime.h>

#define DIM 64
#define NPB 256           // nodes per bucket
#define NPB_SHIFT 8       // bin = dst >> 8
#define THREADS 512
#define K2_U 8
#define K2_EPB (THREADS * K2_U)   // 4096 edges per bin-block = strip size
#define STRIP K2_EPB
#define SRC_BITS 17
#define SRC_MASK ((1u << SRC_BITS) - 1u)
#define NODE_ROWS 160     // rows per node-score block (5 rows/thread)

// Fused kernel: blocks [0,NBLK) bin-sort their 4096-edge chunk into a private
// dense strip (no global atomics, no cursors); blocks [NBLK,...) compute
// per-node scores + out init. Phases are data-independent.
// Total blocks 293+625=918 <= 1024 resident -> single dispatch round.
__global__ __launch_bounds__(THREADS)
void fused_kernel(const float4* __restrict__ x4,
                  const float4* __restrict__ Wrel4,
                  const float* __restrict__ b_rel,
                  const float4* __restrict__ Wroot4,
                  const int* __restrict__ ei,
                  float* __restrict__ s,
                  float* __restrict__ out,
                  unsigned* __restrict__ bucket,        // NBLK*STRIP uints
                  unsigned short* __restrict__ offsT,   // (NB+1) x NBLK u16
                  int E, int NB, int NBLK, int n) {
    __shared__ __align__(16) unsigned lpair[K2_EPB];  // 16 KB
    __shared__ int  hist[THREADS];                    // 2 KB (then excl base)
    __shared__ int  wsum[8];

    int tid = threadIdx.x;

    if (blockIdx.x < NBLK) {
        // ---------------- binning phase ----------------
        int blk = blockIdx.x;
        hist[tid] = 0;
        __syncthreads();                               // barrier 1

        int base = blk * K2_EPB + tid * K2_U;
        int dst[K2_U], src[K2_U], rnk[K2_U], bin[K2_U];
        int have = 0;

        if (base + K2_U <= E) {
            const int4* sv = (const int4*)ei;          // src row
            const int4* dv = (const int4*)(ei + E);    // dst row
            int g = base >> 2;
            int4 s0 = sv[g], s1 = sv[g + 1];
            int4 d0 = dv[g], d1 = dv[g + 1];
            src[0] = s0.x; src[1] = s0.y; src[2] = s0.z; src[3] = s0.w;
            src[4] = s1.x; src[5] = s1.y; src[6] = s1.z; src[7] = s1.w;
            dst[0] = d0.x; dst[1] = d0.y; dst[2] = d0.z; dst[3] = d0.w;
            dst[4] = d1.x; dst[5] = d1.y; dst[6] = d1.z; dst[7] = d1.w;
            have = K2_U;
        } else {
            #pragma unroll
            for (int k = 0; k < K2_U; ++k) {
                int e = base + k;
                if (e < E) {
                    src[k] = ei[e];
                    dst[k] = ei[E + e];
                    have = k + 1;
                }
            }
        }

        #pragma unroll
        for (int k = 0; k < K2_U; ++k) {
            if (k < have) {
                bin[k] = dst[k] >> NPB_SHIFT;
                rnk[k] = atomicAdd(&hist[bin[k]], 1);
            }
        }
        __syncthreads();                               // barrier 2

        int h = hist[tid];

        // per-wave inclusive scan (no barriers)
        int lane = tid & 63;
        int w = tid >> 6;
        int incl = h;
        #pragma unroll
        for (int off = 1; off < 64; off <<= 1) {
            int v = __shfl_up(incl, off);
            if (lane >= off) incl += v;
        }
        if (lane == 63) wsum[w] = incl;
        __syncthreads();                               // barrier 3

        int wb = 0;
        #pragma unroll
        for (int i = 0; i < 8; ++i) wb += (i < w) ? wsum[i] : 0;
        int excl = wb + incl - h;                      // exclusive scan of hist

        // transposed offsets: offsT[bin][blk] (scattered stores, fire&forget;
        // gather reads each row contiguously). Row NB holds strip totals.
        if (tid <= NB)
            offsT[(size_t)tid * NBLK + blk] = (unsigned short)excl;

        hist[tid] = excl;                              // compaction base
        __syncthreads();                               // barrier 4

        #pragma unroll
        for (int k = 0; k < K2_U; ++k) {
            if (k < have) {
                int slot = hist[bin[k]] + rnk[k];      // bin-ordered LDS slot
                lpair[slot] = ((unsigned)(dst[k] & (NPB - 1)) << SRC_BITS)
                              | (unsigned)src[k];
            }
        }
        __syncthreads();                               // barrier 5

        // dense, perfectly-coalesced strip dump (uint4)
        int nE = min(K2_EPB, E - blk * K2_EPB);
        int n4 = (nE + 3) >> 2;
        const uint4* lp4 = (const uint4*)lpair;
        uint4* dp4 = (uint4*)(bucket + (size_t)blk * STRIP);
        for (int i = tid; i < n4; i += THREADS) dp4[i] = lp4[i];
    } else {
        // ---------------- node-score phase ----------------
        int nb = blockIdx.x - NBLK;
        int lane16 = tid & 15;
        int rg = tid >> 4;                  // 0..31
        int rowbase = nb * NODE_ROWS + rg;
        float4 wr = Wrel4[lane16];
        float4 wt = Wroot4[lane16];
        float b0 = b_rel[0];

        float4 xv[5];
        int row[5];
        #pragma unroll
        for (int k = 0; k < 5; ++k) {
            row[k] = rowbase + k * 32;
            xv[k] = (row[k] < n) ? x4[(size_t)row[k] * (DIM / 4) + lane16]
                                 : make_float4(0.f, 0.f, 0.f, 0.f);
        }
        #pragma unroll
        for (int k = 0; k < 5; ++k) {
            float sr = xv[k].x * wr.x + xv[k].y * wr.y
                     + xv[k].z * wr.z + xv[k].w * wr.w;
            float st = xv[k].x * wt.x + xv[k].y * wt.y
                     + xv[k].z * wt.z + xv[k].w * wt.w;
            #pragma unroll
            for (int off = 1; off < 16; off <<= 1) {
                sr += __shfl_xor(sr, off);
                st += __shfl_xor(st, off);
            }
            if (lane16 == 0 && row[k] < n) {
                s[row[k]]   = sr;
                out[row[k]] = st + b0;
            }
        }
    }
}

// Gather: one block per bucket. Stage offs rows b,b+1 (contiguous) into LDS;
// thread t walks strip t's run with uint4-vectorized loads; LDS accumulate;
// plain RMW of disjoint out slice.
__global__ __launch_bounds__(THREADS)
void gather_kernel(const unsigned short* __restrict__ offsT,
                   const unsigned* __restrict__ bucket,
                   const float* __restrict__ s,
                   float* __restrict__ out,
                   int NB, int NBLK, int n) {
    __shared__ float acc[NPB];
    __shared__ unsigned short o0s[THREADS], o1s[THREADS];
    int b = blockIdx.x;
    int tid = threadIdx.x;

    if (tid < NPB) acc[tid] = 0.f;
    for (int t = tid; t < NBLK; t += THREADS) {
        o0s[t] = offsT[(size_t)b * NBLK + t];        // coalesced row read
        o1s[t] = offsT[(size_t)(b + 1) * NBLK + t];
    }
    __syncthreads();

    if (tid < NBLK) {
        int o0 = o0s[tid];
        int o1 = o1s[tid];
        const unsigned* sp = bucket + (size_t)tid * STRIP;
        int i = o0;
        for (; i < o1 && (i & 3); ++i) {
            unsigned p = sp[i];
            atomicAdd(&acc[p >> SRC_BITS], s[p & SRC_MASK]);
        }
        for (; i + 4 <= o1; i += 4) {
            uint4 q = *(const uint4*)(sp + i);
            float v0 = s[q.x & SRC_MASK];
            float v1 = s[q.y & SRC_MASK];
            float v2 = s[q.z & SRC_MASK];
            float v3 = s[q.w & SRC_MASK];
            atomicAdd(&acc[q.x >> SRC_BITS], v0);
            atomicAdd(&acc[q.y >> SRC_BITS], v1);
            atomicAdd(&acc[q.z >> SRC_BITS], v2);
            atomicAdd(&acc[q.w >> SRC_BITS], v3);
        }
        for (; i < o1; ++i) {
            unsigned p = sp[i];
            atomicAdd(&acc[p >> SRC_BITS], s[p & SRC_MASK]);
        }
    }
    __syncthreads();

    if (tid < NPB) {
        int g = b * NPB + tid;
        if (g < n) out[g] += acc[tid];
    }
}

extern "C" void kernel_launch(void* const* d_in, const int* in_sizes, int n_in,
                              void* d_out, int out_size, void* d_ws, size_t ws_size,
                              hipStream_t stream) {
    const float* x      = (const float*)d_in[0];
    const int*   ei     = (const int*)d_in[1];
    const float* W_rel  = (const float*)d_in[2];
    const float* b_rel  = (const float*)d_in[3];
    const float* W_root = (const float*)d_in[4];
    float* out = (float*)d_out;

    int n = out_size;                 // N_NODES = 100000
    int E = in_sizes[1] / 2;          // 1200000

    int NB   = (n + NPB - 1) / NPB;          // 391 buckets (<= THREADS)
    int NBLK = (E + K2_EPB - 1) / K2_EPB;    // 293 strips

    // ws layout: s [n f32] | offsT [(NB+1)*NBLK u16] | bucket [NBLK*STRIP u32]
    float* s = (float*)d_ws;
    size_t off = ((size_t)n * 4 + 255) & ~(size_t)255;
    unsigned short* offsT = (unsigned short*)((char*)d_ws + off);
    off += ((size_t)(NB + 1) * NBLK * 2 + 255) & ~(size_t)255;
    unsigned* bucket = (unsigned*)((char*)d_ws + off);

    // 1) fused: strip-binning blocks + node-score blocks (918 blocks total)
    int NODEBLKS = (n + NODE_ROWS - 1) / NODE_ROWS;  // 625
    fused_kernel<<<NBLK + NODEBLKS, THREADS, 0, stream>>>(
        (const float4*)x, (const float4*)W_rel, b_rel, (const float4*)W_root,
        ei, s, out, bucket, offsT, E, NB, NBLK, n);

    // 2) per-bucket run-walk accumulate + disjoint out RMW
    gather_kernel<<<NB, THREADS, 0, stream>>>(offsT, bucket, s, out, NB, NBLK, n);
}